// Round 1
// baseline (245.264 us; speedup 1.0000x reference)
//
#include <hip/hip_runtime.h>

// Decomposition (verified passing):
//   um[b,h,s1,e] = sum_s2 v[b, s1*64+s2, h, e]
//   vm[b,h,s2,e] = sum_s1 v[b, s1*64+s2, h, e]
//   RxV = W2 @ vm, RxU = W2 @ um,  W2[t][k] = w[h][(t+64-k) mod 127]
//   out[b, s1*64+s2, h, e] = RxV[s2] + RxU[s1]
//
// ws layout (f4 = float-x4 units):
//   vm_part[slice 4][b 8][s2 64][he4 256]  @ 0        (524288 f4, 8.4 MB)
//   um     [b 8][s1 64][he4 256]           @ 524288   (131072 f4)

typedef float f4 __attribute__((ext_vector_type(4)));

// ---------------- K1: reduction pass (reads v once, nontemporal) ----------
// grid 1024 = (b:8, slice:4, hcb:32), 256 threads = (rowth:32, slot:8)
__global__ __launch_bounds__(256, 4) void k1_reduce(
    const f4* __restrict__ v4,
    f4* __restrict__ vm_part,
    f4* __restrict__ um_ws)
{
    __shared__ f4 um_w[4][16][8];        // [wave][s1l][slot], 8 KB

    const int bid   = blockIdx.x;
    const int hcb   = bid & 31;
    const int slice = (bid >> 5) & 3;
    const int b     = bid >> 7;
    const int t     = threadIdx.x;
    const int slot  = t & 7;
    const int rowth = t >> 3;            // 0..31  (s2 = rowth, rowth+32)
    const int wv    = t >> 6;
    const int he4   = hcb * 8 + slot;    // 0..255

    const f4* base = v4 + ((size_t)(b * 4096 + slice * 1024 + rowth) * 256 + he4);

    f4 um_acc[16];
#pragma unroll
    for (int j = 0; j < 16; ++j) um_acc[j] = (f4)0.f;
    f4 vm0 = (f4)0.f, vm1 = (f4)0.f;

#pragma unroll
    for (int s1l = 0; s1l < 16; ++s1l) {
        f4 a  = __builtin_nontemporal_load(base + s1l * 16384);          // s2 = rowth
        f4 b4 = __builtin_nontemporal_load(base + s1l * 16384 + 8192);   // s2 = rowth+32
        um_acc[s1l] += a + b4;
        vm0 += a;
        vm1 += b4;
    }

    // vm: thread-local complete over this slice -> direct store (cached; K2 rereads)
    vm_part[((size_t)(slice * 8 + b) * 64 + rowth) * 256 + he4]      = vm0;
    vm_part[((size_t)(slice * 8 + b) * 64 + rowth + 32) * 256 + he4] = vm1;

    // um: reduce over rowth (lane bits 3,4,5 within wave), then 4 waves via LDS
#pragma unroll
    for (int j = 0; j < 16; ++j) {
        f4 s = um_acc[j];
        s.x += __shfl_xor(s.x, 8);  s.y += __shfl_xor(s.y, 8);
        s.z += __shfl_xor(s.z, 8);  s.w += __shfl_xor(s.w, 8);
        s.x += __shfl_xor(s.x, 16); s.y += __shfl_xor(s.y, 16);
        s.z += __shfl_xor(s.z, 16); s.w += __shfl_xor(s.w, 16);
        s.x += __shfl_xor(s.x, 32); s.y += __shfl_xor(s.y, 32);
        s.z += __shfl_xor(s.z, 32); s.w += __shfl_xor(s.w, 32);
        if ((t & 63) < 8) um_w[wv][j][slot] = s;
    }
    __syncthreads();

    if (t < 128) {
        const int s1l = t >> 3;
        const int sl2 = t & 7;
        f4 s = um_w[0][s1l][sl2] + um_w[1][s1l][sl2]
             + um_w[2][s1l][sl2] + um_w[3][s1l][sl2];
        um_ws[((size_t)b * 64 + slice * 16 + s1l) * 256 + hcb * 8 + sl2] = s;
    }
}

// ---------------- K2: fused slice-reduce + dual matvec + broadcast write ----
// grid 1024 = (s1g:8 high, b:8, h:16 low), 256 threads = (tg:16, e4:16)
// s1g in the HIGH bits: the 8 blocks sharing (b,h) are 128 apart in bid ->
// same XCD under round-robin dispatch -> vm_part re-reads stay L2-local.
__global__ __launch_bounds__(256) void k2_fused(
    const f4* __restrict__ vm_part,
    const f4* __restrict__ um_ws,
    const float* __restrict__ w,
    f4* __restrict__ out4)
{
    __shared__ f4 vm_s[64][16];          // after compute: reused as rxv[t][e4]
    __shared__ f4 um_s[64][16];          // after compute: rows 0..7 = rxu[s1l][e4]
    __shared__ float w_s[128];           // w_s[127] = w[0] (mod-127 wrap)

    const int bid = blockIdx.x;
    const int s1g = bid >> 7;            // 0..7
    const int b   = (bid >> 4) & 7;
    const int h   = bid & 15;
    const int t   = threadIdx.x;
    const int e4  = t & 15;
    const int tg  = t >> 4;              // 0..15

    if (t < 128) w_s[t] = w[h * 127 + (t == 127 ? 0 : t)];

#pragma unroll
    for (int r = 0; r < 4; ++r) {
        const int k = tg + 16 * r;
        f4 acc = vm_part[((size_t)(0 * 8 + b) * 64 + k) * 256 + h * 16 + e4]
               + vm_part[((size_t)(1 * 8 + b) * 64 + k) * 256 + h * 16 + e4]
               + vm_part[((size_t)(2 * 8 + b) * 64 + k) * 256 + h * 16 + e4]
               + vm_part[((size_t)(3 * 8 + b) * 64 + k) * 256 + h * 16 + e4];
        vm_s[k][e4] = acc;
        um_s[k][e4] = um_ws[((size_t)b * 64 + k) * 256 + h * 16 + e4];
    }
    __syncthreads();

    // dual matvec: each tg computes RxV[t = 4tg .. 4tg+3] (sliding-register
    // weights) and RxU[s1 = s1g*8 + (tg&7)] (its own sliding weight).
    const int T0 = tg * 4;
    const int s1loc = tg & 7;
    const int s1w = s1g * 8 + s1loc;
    f4 aV0 = (f4)0.f, aV1 = (f4)0.f, aV2 = (f4)0.f, aV3 = (f4)0.f;
    f4 aU  = (f4)0.f;
    float W0 = w_s[T0 + 64], W1 = w_s[T0 + 65];
    float W2v = w_s[T0 + 66], W3v = w_s[T0 + 67];
    float WU = w_s[s1w + 64];
    for (int k = 0; k < 64; ++k) {
        f4 vmv = vm_s[k][e4];
        f4 umv = um_s[k][e4];
        aV0 += W0 * vmv;  aV1 += W1 * vmv;
        aV2 += W2v * vmv; aV3 += W3v * vmv;
        aU  += WU * umv;
        if (k < 63) {
            float nw = w_s[T0 + 63 - k];
            W3v = W2v; W2v = W1; W1 = W0; W0 = nw;
            WU = w_s[s1w + 63 - k];
        }
    }
    __syncthreads();                     // everyone done reading vm_s/um_s
    vm_s[T0 + 0][e4] = aV0; vm_s[T0 + 1][e4] = aV1;
    vm_s[T0 + 2][e4] = aV2; vm_s[T0 + 3][e4] = aV3;
    if (tg < 8) um_s[tg][e4] = aU;       // rxu for this block's 8 s1 rows
    __syncthreads();

    // write: 8 s1 rows (s1g*8..+7) x 64 s2, (h, e4) slice; NT streaming
    const f4 rv0 = vm_s[tg +  0][e4];
    const f4 rv1 = vm_s[tg + 16][e4];
    const f4 rv2 = vm_s[tg + 32][e4];
    const f4 rv3 = vm_s[tg + 48][e4];
    f4* obase = out4 + (size_t)b * 4096 * 256 + (size_t)h * 16 + e4;
#pragma unroll
    for (int s1l = 0; s1l < 8; ++s1l) {
        const f4 ru = um_s[s1l][e4];
        f4* orow = obase + (size_t)(s1g * 8 + s1l) * 64 * 256;
        __builtin_nontemporal_store(ru + rv0, orow + (size_t)(tg +  0) * 256);
        __builtin_nontemporal_store(ru + rv1, orow + (size_t)(tg + 16) * 256);
        __builtin_nontemporal_store(ru + rv2, orow + (size_t)(tg + 32) * 256);
        __builtin_nontemporal_store(ru + rv3, orow + (size_t)(tg + 48) * 256);
    }
}

extern "C" void kernel_launch(void* const* d_in, const int* in_sizes, int n_in,
                              void* d_out, int out_size, void* d_ws, size_t ws_size,
                              hipStream_t stream) {
    const f4*    v4 = (const f4*)d_in[0];     // [8, 4096, 16, 64] fp32
    const float* w  = (const float*)d_in[1];  // [1, 16, 127] fp32
    f4* out4 = (f4*)d_out;                    // [8, 4096, 16, 64] fp32

    f4* ws4     = (f4*)d_ws;
    f4* vm_part = ws4;                        // 524288 f4
    f4* um_ws   = ws4 + 524288;               // 131072 f4 (total 10.5 MB)

    k1_reduce<<<1024, 256, 0, stream>>>(v4, vm_part, um_ws);
    k2_fused<<<1024, 256, 0, stream>>>(vm_part, um_ws, w, out4);
}